// Round 3
// baseline (24.146 us; speedup 1.0000x reference)
//
#include <hip/hip_runtime.h>

// MonoDispExp: per-pixel affine flow-consistency fit on a 3x3 neighborhood.
// flow: (B=4, 2, H=256, W=832) float32.
// d_out: [0..BHW) mask as 0/1 float, [BHW..2BHW) exp.
//
// 4 pixels/thread, channel-packed float2 math.
// Interior algebra (validated absmax 0.0 in rounds 1-2):
//   pp = diag(6), ppinv = I/6, aff = M/6 where
//   m00 = 6 + colsumR(fx) - colsumL(fx);  m01 = rowsumB(fx) - rowsumT(fx)
//   m10 =     colsumR(fy) - colsumL(fy);  m11 = 6 + rowsumB(fy) - rowsumT(fy)
//   residual_k = (dj*U + di*V + center) - f_neighbor, U=(a00-1,a10), V=(a01,a11-1)
//   center term (k=4) is exactly 0.
// Border pixels (0.5%) use the rolled two-pass general path.

#define BB 4
#define HH 256
#define WW 832
#define HWsz (HH * WW)
#define GX (WW / 4)

__device__ __forceinline__ float fsqrt(float x) { return __builtin_amdgcn_sqrtf(x); }

struct pf2 { float x, y; };
__device__ __forceinline__ pf2 mkf2(float a, float b) { pf2 r; r.x = a; r.y = b; return r; }
__device__ __forceinline__ pf2 operator+(pf2 a, pf2 b) { return mkf2(a.x + b.x, a.y + b.y); }
__device__ __forceinline__ pf2 operator-(pf2 a, pf2 b) { return mkf2(a.x - b.x, a.y - b.y); }

__device__ __forceinline__ float rdot(pf2 c, pf2 f) {
  const float rx = c.x - f.x, ry = c.y - f.y;
  return fsqrt(rx * rx + ry * ry);
}

// General path (zero-pad-minus-center semantics), two-pass, rolled loops to
// keep register pressure low. Matches round-1/2 validated arithmetic.
__device__ void general_pixel(const float* __restrict__ fx, const float* __restrict__ fy,
                              int x, int y, float& mask_o, float& exp_o) {
  const int o = y * WW + x;
  const float fxc = fx[o], fyc = fy[o];
  float pp00 = 0.f, pp01 = 0.f, pp11 = 0.f;
  float m00 = 0.f, m01 = 0.f, m10 = 0.f, m11 = 0.f;
#pragma unroll 1
  for (int k = 0; k < 9; ++k) {
    const int di = k / 3 - 1, dj = k - (k / 3) * 3 - 1;
    const int yy = y + di, xx = x + dj;
    const bool in = (yy >= 0) && (yy < HH) && (xx >= 0) && (xx < WW);
    float prx, pry, ptx, pty;
    if (in) {
      prx = (float)dj; pry = (float)di;
      ptx = (float)dj + fx[yy * WW + xx] - fxc;
      pty = (float)di + fy[yy * WW + xx] - fyc;
    } else {
      prx = -(float)x; pry = -(float)y;
      ptx = -((float)x + fxc); pty = -((float)y + fyc);
    }
    pp00 += prx * prx; pp01 += prx * pry; pp11 += pry * pry;
    m00 += ptx * prx; m01 += ptx * pry; m10 += pty * prx; m11 += pty * pry;
  }
  const float det = fmaxf(pp00 * pp11 - pp01 * pp01, 1e-10f);
  const float i00 = pp11 / det, i01 = -pp01 / det, i11 = pp00 / det;
  const float a00 = m00 * i00 + m01 * i01;
  const float a01 = m00 * i01 + m01 * i11;
  const float a10 = m10 * i00 + m11 * i01;
  const float a11 = m10 * i01 + m11 * i11;
  float errsum = 0.f;
#pragma unroll 1
  for (int k = 0; k < 9; ++k) {
    const int di = k / 3 - 1, dj = k - (k / 3) * 3 - 1;
    const int yy = y + di, xx = x + dj;
    const bool in = (yy >= 0) && (yy < HH) && (xx >= 0) && (xx < WW);
    float prx, pry, ptx, pty;
    if (in) {
      prx = (float)dj; pry = (float)di;
      ptx = (float)dj + fx[yy * WW + xx] - fxc;
      pty = (float)di + fy[yy * WW + xx] - fyc;
    } else {
      prx = -(float)x; pry = -(float)y;
      ptx = -((float)x + fxc); pty = -((float)y + fyc);
    }
    const float rx = a00 * prx + a01 * pry - ptx;
    const float ry = a10 * prx + a11 * pry - pty;
    errsum += fsqrt(rx * rx + ry * ry);
  }
  const float error = errsum / 9.0f;
  const float ex = fsqrt(fmaxf(fabsf(a00 * a11 - a10 * a01), 1e-10f));
  mask_o = ((ex > 0.5f) && (ex < 2.0f) && (error < 0.1f)) ? 1.0f : 0.0f;
  exp_o = (error > 0.1f) ? 1.0f : fminf(fmaxf(ex, 0.5f), 2.0f);
}

__global__ __launch_bounds__(256, 2) void monodisp4(
    const float* __restrict__ flow,
    float* __restrict__ out_mask,
    float* __restrict__ out_exp) {
  const int gid = blockIdx.x * 256 + threadIdx.x;  // [0, 212992)
  const int gx = gid % GX;
  const int t = gid / GX;
  const int y = t % HH;
  const int b = t / HH;
  const int x0 = gx * 4;

  const float* __restrict__ fx = flow + (b * 2 + 0) * HWsz;
  const float* __restrict__ fy = flow + (b * 2 + 1) * HWsz;

  float m0, m1, m2, m3, e0, e1, e2, e3;
  const bool rowborder = (y == 0) || (y == HH - 1);

  if (!rowborder) {
    const int o = y * WW + x0;
    const int lm = (gx == 0) ? 0 : -1;        // left edge col offset (clamped; value
    const int rp = (gx == GX - 1) ? 3 : 4;    // unused for the border pixel, recomputed)

    pf2 f0[6], f1[6], f2r[6];
    {
      const float4 vx = *reinterpret_cast<const float4*>(fx + (o - WW));
      const float4 vy = *reinterpret_cast<const float4*>(fy + (o - WW));
      f0[0] = mkf2(fx[o - WW + lm], fy[o - WW + lm]);
      f0[1] = mkf2(vx.x, vy.x); f0[2] = mkf2(vx.y, vy.y);
      f0[3] = mkf2(vx.z, vy.z); f0[4] = mkf2(vx.w, vy.w);
      f0[5] = mkf2(fx[o - WW + rp], fy[o - WW + rp]);
    }
    {
      const float4 vx = *reinterpret_cast<const float4*>(fx + o);
      const float4 vy = *reinterpret_cast<const float4*>(fy + o);
      f1[0] = mkf2(fx[o + lm], fy[o + lm]);
      f1[1] = mkf2(vx.x, vy.x); f1[2] = mkf2(vx.y, vy.y);
      f1[3] = mkf2(vx.z, vy.z); f1[4] = mkf2(vx.w, vy.w);
      f1[5] = mkf2(fx[o + rp], fy[o + rp]);
    }
    {
      const float4 vx = *reinterpret_cast<const float4*>(fx + (o + WW));
      const float4 vy = *reinterpret_cast<const float4*>(fy + (o + WW));
      f2r[0] = mkf2(fx[o + WW + lm], fy[o + WW + lm]);
      f2r[1] = mkf2(vx.x, vy.x); f2r[2] = mkf2(vx.y, vy.y);
      f2r[3] = mkf2(vx.z, vy.z); f2r[4] = mkf2(vx.w, vy.w);
      f2r[5] = mkf2(fx[o + WW + rp], fy[o + WW + rp]);
    }

    pf2 cs[6];
#pragma unroll
    for (int j = 0; j < 6; ++j) cs[j] = f0[j] + f1[j] + f2r[j];

    const float inv6 = 1.0f / 6.0f;
    const float inv9 = 1.0f / 9.0f;

#pragma unroll
    for (int i = 0; i < 4; ++i) {
      const pf2 c = f1[i + 1];
      const pf2 mc = cs[i + 2] - cs[i];                       // (m00-6, m10)
      const pf2 rt = f0[i] + f0[i + 1] + f0[i + 2];
      const pf2 rb = f2r[i] + f2r[i + 1] + f2r[i + 2];
      const pf2 mr = rb - rt;                                 // (m01, m11-6)
      const float a00 = (6.f + mc.x) * inv6;
      const float a10 = mc.y * inv6;
      const float a01 = mr.x * inv6;
      const float a11 = (6.f + mr.y) * inv6;
      const pf2 U = mkf2(a00 - 1.f, a10);
      const pf2 V = mkf2(a01, a11 - 1.f);
      const pf2 Pv = c + U;
      const pf2 Mv = c - U;
      float errsum = 0.f;
      errsum += rdot(Mv - V, f0[i]);       // k0 (-1,-1)
      errsum += rdot(c - V, f0[i + 1]);    // k1 ( 0,-1)
      errsum += rdot(Pv - V, f0[i + 2]);   // k2 ( 1,-1)
      errsum += rdot(Mv, f1[i]);           // k3 (-1, 0)
      errsum += rdot(Pv, f1[i + 2]);       // k5 ( 1, 0)
      errsum += rdot(Mv + V, f2r[i]);      // k6 (-1, 1)
      errsum += rdot(c + V, f2r[i + 1]);   // k7 ( 0, 1)
      errsum += rdot(Pv + V, f2r[i + 2]);  // k8 ( 1, 1)
      const float error = errsum * inv9;
      const float ex = fsqrt(fmaxf(fabsf(a00 * a11 - a10 * a01), 1e-10f));
      const float mo = ((ex > 0.5f) && (ex < 2.0f) && (error < 0.1f)) ? 1.0f : 0.0f;
      const float eo = (error > 0.1f) ? 1.0f : fminf(fmaxf(ex, 0.5f), 2.0f);
      if (i == 0) { m0 = mo; e0 = eo; }
      else if (i == 1) { m1 = mo; e1 = eo; }
      else if (i == 2) { m2 = mo; e2 = eo; }
      else { m3 = mo; e3 = eo; }
    }
    if (gx == 0)      general_pixel(fx, fy, 0, y, m0, e0);
    if (gx == GX - 1) general_pixel(fx, fy, WW - 1, y, m3, e3);
  } else {
    general_pixel(fx, fy, x0 + 0, y, m0, e0);
    general_pixel(fx, fy, x0 + 1, y, m1, e1);
    general_pixel(fx, fy, x0 + 2, y, m2, e2);
    general_pixel(fx, fy, x0 + 3, y, m3, e3);
  }

  const int oo = b * HWsz + y * WW + x0;
  float4 mv; mv.x = m0; mv.y = m1; mv.z = m2; mv.w = m3;
  float4 ev; ev.x = e0; ev.y = e1; ev.z = e2; ev.w = e3;
  *reinterpret_cast<float4*>(out_mask + oo) = mv;
  *reinterpret_cast<float4*>(out_exp + oo) = ev;
}

extern "C" void kernel_launch(void* const* d_in, const int* in_sizes, int n_in,
                              void* d_out, int out_size, void* d_ws, size_t ws_size,
                              hipStream_t stream) {
  (void)in_sizes; (void)n_in; (void)d_ws; (void)ws_size; (void)out_size;
  const float* flow = (const float*)d_in[0];
  float* out = (float*)d_out;
  float* out_mask = out;
  float* out_exp = out + (size_t)BB * HH * WW;

  const int total_threads = BB * HH * GX;   // 212992 = 832 * 256 exactly
  const int block = 256;
  const int grid = total_threads / block;
  monodisp4<<<grid, block, 0, stream>>>(flow, out_mask, out_exp);
}

// Round 4
// 18.109 us; speedup vs baseline: 1.3334x; 1.3334x over previous
//
#include <hip/hip_runtime.h>

// MonoDispExp: per-pixel affine flow-consistency fit on a 3x3 neighborhood.
// flow: (B=4, 2, H=256, W=832) float32.
// d_out: [0..BHW) mask as 0/1 float, [BHW..2BHW) exp.
//
// Structure (round 4):
//  - Blocks [0, N_INT_BLOCKS): interior pixels only (rows 1..254, cols 1..830),
//    2 px/thread, aligned float2 loads, branch-free uniform waves.
//    Interior algebra validated bit-exact in round 3 (absmax 0.0):
//      pp = diag(6), aff = M/6, U=(a00-1,a10), V=(a01,a11-1),
//      residual_k = (dj*U + di*V + center) - f_neighbor, center term == 0.
//  - Blocks [N_INT_BLOCKS, +N_BORDER_BLOCKS): all border pixels via the
//    general zero-pad-minus-center path (validated rounds 1-3), running
//    concurrently in their own waves (no divergence inside interior waves).

#define BB 4
#define HH 256
#define WW 832
#define HWsz (HH * WW)

#define INT_ROWS (HH - 2)                           // 254
#define POS_PER_ROW ((WW - 2) / 2)                  // 415 pixel-pairs per row
#define N_INT_THREADS (BB * INT_ROWS * POS_PER_ROW) // 421640
#define N_INT_BLOCKS ((N_INT_THREADS + 255) / 256)  // 1648
#define BORDER_PER_B (2 * WW + 2 * (HH - 2))        // 2172
#define N_BORDER (BB * BORDER_PER_B)                // 8688
#define N_BORDER_BLOCKS ((N_BORDER + 255) / 256)    // 34

__device__ __forceinline__ float fsqrt(float x) { return __builtin_amdgcn_sqrtf(x); }

struct pf2 { float x, y; };
__device__ __forceinline__ pf2 mkf2(float a, float b) { pf2 r; r.x = a; r.y = b; return r; }
__device__ __forceinline__ pf2 operator+(pf2 a, pf2 b) { return mkf2(a.x + b.x, a.y + b.y); }
__device__ __forceinline__ pf2 operator-(pf2 a, pf2 b) { return mkf2(a.x - b.x, a.y - b.y); }

__device__ __forceinline__ float rdot(pf2 c, pf2 f) {
  const float rx = c.x - f.x, ry = c.y - f.y;
  return fsqrt(rx * rx + ry * ry);
}

// ---- interior pixel, window cols P..P+2 of g[3][4] (compile-time P) ----
template <int P>
__device__ __forceinline__ void interior_px(const pf2 (&g)[3][4], float& mo, float& eo) {
  const pf2 csl = g[0][P] + g[1][P] + g[2][P];
  const pf2 csr = g[0][P + 2] + g[1][P + 2] + g[2][P + 2];
  const pf2 mc = csr - csl;                               // (m00-6, m10)
  const pf2 rt = g[0][P] + g[0][P + 1] + g[0][P + 2];
  const pf2 rb = g[2][P] + g[2][P + 1] + g[2][P + 2];
  const pf2 mr = rb - rt;                                 // (m01, m11-6)

  const float inv6 = 1.0f / 6.0f;
  const float inv9 = 1.0f / 9.0f;
  const float a00 = (6.f + mc.x) * inv6;
  const float a10 = mc.y * inv6;
  const float a01 = mr.x * inv6;
  const float a11 = (6.f + mr.y) * inv6;

  const pf2 c = g[1][P + 1];
  const pf2 U = mkf2(a00 - 1.f, a10);
  const pf2 V = mkf2(a01, a11 - 1.f);
  const pf2 Pv = c + U;
  const pf2 Mv = c - U;

  float errsum = 0.f;
  errsum += rdot(Mv - V, g[0][P]);      // k0 (-1,-1)
  errsum += rdot(c - V,  g[0][P + 1]);  // k1 ( 0,-1)
  errsum += rdot(Pv - V, g[0][P + 2]);  // k2 ( 1,-1)
  errsum += rdot(Mv,     g[1][P]);      // k3 (-1, 0)
  errsum += rdot(Pv,     g[1][P + 2]);  // k5 ( 1, 0)
  errsum += rdot(Mv + V, g[2][P]);      // k6 (-1, 1)
  errsum += rdot(c + V,  g[2][P + 1]);  // k7 ( 0, 1)
  errsum += rdot(Pv + V, g[2][P + 2]);  // k8 ( 1, 1)
  const float error = errsum * inv9;

  const float ex = fsqrt(fmaxf(fabsf(a00 * a11 - a10 * a01), 1e-10f));
  mo = ((ex > 0.5f) && (ex < 2.0f) && (error < 0.1f)) ? 1.0f : 0.0f;
  eo = (error > 0.1f) ? 1.0f : fminf(fmaxf(ex, 0.5f), 2.0f);
}

// ---- general path (zero-pad-minus-center), two-pass rolled, low VGPR ----
__device__ void general_pixel(const float* __restrict__ fx, const float* __restrict__ fy,
                              int x, int y, float& mask_o, float& exp_o) {
  const int o = y * WW + x;
  const float fxc = fx[o], fyc = fy[o];
  float pp00 = 0.f, pp01 = 0.f, pp11 = 0.f;
  float m00 = 0.f, m01 = 0.f, m10 = 0.f, m11 = 0.f;
#pragma unroll 1
  for (int k = 0; k < 9; ++k) {
    const int di = k / 3 - 1, dj = k - (k / 3) * 3 - 1;
    const int yy = y + di, xx = x + dj;
    const bool in = (yy >= 0) && (yy < HH) && (xx >= 0) && (xx < WW);
    float prx, pry, ptx, pty;
    if (in) {
      prx = (float)dj; pry = (float)di;
      ptx = (float)dj + fx[yy * WW + xx] - fxc;
      pty = (float)di + fy[yy * WW + xx] - fyc;
    } else {
      prx = -(float)x; pry = -(float)y;
      ptx = -((float)x + fxc); pty = -((float)y + fyc);
    }
    pp00 += prx * prx; pp01 += prx * pry; pp11 += pry * pry;
    m00 += ptx * prx; m01 += ptx * pry; m10 += pty * prx; m11 += pty * pry;
  }
  const float det = fmaxf(pp00 * pp11 - pp01 * pp01, 1e-10f);
  const float i00 = pp11 / det, i01 = -pp01 / det, i11 = pp00 / det;
  const float a00 = m00 * i00 + m01 * i01;
  const float a01 = m00 * i01 + m01 * i11;
  const float a10 = m10 * i00 + m11 * i01;
  const float a11 = m10 * i01 + m11 * i11;
  float errsum = 0.f;
#pragma unroll 1
  for (int k = 0; k < 9; ++k) {
    const int di = k / 3 - 1, dj = k - (k / 3) * 3 - 1;
    const int yy = y + di, xx = x + dj;
    const bool in = (yy >= 0) && (yy < HH) && (xx >= 0) && (xx < WW);
    float prx, pry, ptx, pty;
    if (in) {
      prx = (float)dj; pry = (float)di;
      ptx = (float)dj + fx[yy * WW + xx] - fxc;
      pty = (float)di + fy[yy * WW + xx] - fyc;
    } else {
      prx = -(float)x; pry = -(float)y;
      ptx = -((float)x + fxc); pty = -((float)y + fyc);
    }
    const float rx = a00 * prx + a01 * pry - ptx;
    const float ry = a10 * prx + a11 * pry - pty;
    errsum += fsqrt(rx * rx + ry * ry);
  }
  const float error = errsum / 9.0f;
  const float ex = fsqrt(fmaxf(fabsf(a00 * a11 - a10 * a01), 1e-10f));
  mask_o = ((ex > 0.5f) && (ex < 2.0f) && (error < 0.1f)) ? 1.0f : 0.0f;
  exp_o = (error > 0.1f) ? 1.0f : fminf(fmaxf(ex, 0.5f), 2.0f);
}

__global__ __launch_bounds__(256) void monodisp_split(
    const float* __restrict__ flow,
    float* __restrict__ out_mask,
    float* __restrict__ out_exp) {
  if (blockIdx.x < N_INT_BLOCKS) {
    // ---------- interior: 2 px/thread, uniform waves ----------
    const int tid = blockIdx.x * 256 + threadIdx.x;
    if (tid >= N_INT_THREADS) return;
    const int pos = tid % POS_PER_ROW;
    const int t = tid / POS_PER_ROW;          // [0, 1016)
    const int y = t % INT_ROWS + 1;           // 1..254
    const int b = t / INT_ROWS;
    const int x0 = 1 + 2 * pos;               // odd; pixels x0, x0+1 in 1..830

    const float* __restrict__ fx = flow + (b * 2 + 0) * HWsz;
    const float* __restrict__ fy = flow + (b * 2 + 1) * HWsz;
    const int base = (y - 1) * WW + (x0 - 1); // even -> 8B aligned

    pf2 g[3][4];
#pragma unroll
    for (int r = 0; r < 3; ++r) {
      const float2 ax = *reinterpret_cast<const float2*>(fx + base + r * WW);
      const float2 bx = *reinterpret_cast<const float2*>(fx + base + r * WW + 2);
      const float2 ay = *reinterpret_cast<const float2*>(fy + base + r * WW);
      const float2 by = *reinterpret_cast<const float2*>(fy + base + r * WW + 2);
      g[r][0] = mkf2(ax.x, ay.x);
      g[r][1] = mkf2(ax.y, ay.y);
      g[r][2] = mkf2(bx.x, by.x);
      g[r][3] = mkf2(bx.y, by.y);
    }

    float m0, e0, m1, e1;
    interior_px<0>(g, m0, e0);
    interior_px<1>(g, m1, e1);

    const int oo = b * HWsz + y * WW + x0;
    out_mask[oo] = m0;
    out_mask[oo + 1] = m1;
    out_exp[oo] = e0;
    out_exp[oo + 1] = e1;
  } else {
    // ---------- border: dedicated blocks, general path ----------
    const int btid = (blockIdx.x - N_INT_BLOCKS) * 256 + threadIdx.x;
    if (btid >= N_BORDER) return;
    const int b = btid / BORDER_PER_B;
    const int r = btid % BORDER_PER_B;
    int x, y;
    if (r < WW) { y = 0; x = r; }
    else if (r < 2 * WW) { y = HH - 1; x = r - WW; }
    else if (r < 2 * WW + (HH - 2)) { x = 0; y = r - 2 * WW + 1; }
    else { x = WW - 1; y = r - (2 * WW + (HH - 2)) + 1; }

    const float* __restrict__ fx = flow + (b * 2 + 0) * HWsz;
    const float* __restrict__ fy = flow + (b * 2 + 1) * HWsz;
    float mo, eo;
    general_pixel(fx, fy, x, y, mo, eo);
    const int oo = b * HWsz + y * WW + x;
    out_mask[oo] = mo;
    out_exp[oo] = eo;
  }
}

extern "C" void kernel_launch(void* const* d_in, const int* in_sizes, int n_in,
                              void* d_out, int out_size, void* d_ws, size_t ws_size,
                              hipStream_t stream) {
  (void)in_sizes; (void)n_in; (void)d_ws; (void)ws_size; (void)out_size;
  const float* flow = (const float*)d_in[0];
  float* out = (float*)d_out;
  float* out_mask = out;
  float* out_exp = out + (size_t)BB * HH * WW;

  const int grid = N_INT_BLOCKS + N_BORDER_BLOCKS;  // 1682
  monodisp_split<<<grid, 256, 0, stream>>>(flow, out_mask, out_exp);
}

// Round 5
// 12.504 us; speedup vs baseline: 1.9311x; 1.4482x over previous
//
#include <hip/hip_runtime.h>

// MonoDispExp: per-pixel affine flow-consistency fit on a 3x3 neighborhood.
// flow: (B=4, 2, H=256, W=832) float32.
// d_out: [0..BHW) mask as 0/1 float, [BHW..2BHW) exp.
//
// Structure (round 5):
//  - Blocks [0, N_INT_BLOCKS): interior pixels only (rows 1..254, cols 1..830),
//    2 px/thread, aligned float2 loads, branch-free uniform waves.
//    Interior algebra validated bit-exact (absmax 0.0, rounds 3-4):
//      pp = diag(6), aff = M/6, U=(a00-1,a10), V=(a01,a11-1),
//      residual_k = (dj*U + di*V + center) - f_neighbor, center term == 0.
//  - Blocks [N_INT_BLOCKS, ...): border pixels via the FULLY-UNROLLED general
//    zero-pad-minus-center path (round-1 code, absmax 0.0). Rounds 3-4 showed
//    the rolled version serializes load latency -> multi-us wave tail; the
//    unrolled version issues all 18 loads up-front.

#define BB 4
#define HH 256
#define WW 832
#define HWsz (HH * WW)

#define INT_ROWS (HH - 2)                           // 254
#define POS_PER_ROW ((WW - 2) / 2)                  // 415 pixel-pairs per row
#define N_INT_THREADS (BB * INT_ROWS * POS_PER_ROW) // 421640
#define N_INT_BLOCKS ((N_INT_THREADS + 255) / 256)  // 1648
#define BORDER_PER_B (2 * WW + 2 * (HH - 2))        // 2172
#define N_BORDER (BB * BORDER_PER_B)                // 8688
#define N_BORDER_BLOCKS ((N_BORDER + 255) / 256)    // 34

__device__ __forceinline__ float fsqrt(float x) { return __builtin_amdgcn_sqrtf(x); }

struct pf2 { float x, y; };
__device__ __forceinline__ pf2 mkf2(float a, float b) { pf2 r; r.x = a; r.y = b; return r; }
__device__ __forceinline__ pf2 operator+(pf2 a, pf2 b) { return mkf2(a.x + b.x, a.y + b.y); }
__device__ __forceinline__ pf2 operator-(pf2 a, pf2 b) { return mkf2(a.x - b.x, a.y - b.y); }

__device__ __forceinline__ float rdot(pf2 c, pf2 f) {
  const float rx = c.x - f.x, ry = c.y - f.y;
  return fsqrt(rx * rx + ry * ry);
}

// ---- interior pixel, window cols P..P+2 of g[3][4] (compile-time P) ----
template <int P>
__device__ __forceinline__ void interior_px(const pf2 (&g)[3][4], float& mo, float& eo) {
  const pf2 csl = g[0][P] + g[1][P] + g[2][P];
  const pf2 csr = g[0][P + 2] + g[1][P + 2] + g[2][P + 2];
  const pf2 mc = csr - csl;                               // (m00-6, m10)
  const pf2 rt = g[0][P] + g[0][P + 1] + g[0][P + 2];
  const pf2 rb = g[2][P] + g[2][P + 1] + g[2][P + 2];
  const pf2 mr = rb - rt;                                 // (m01, m11-6)

  const float inv6 = 1.0f / 6.0f;
  const float inv9 = 1.0f / 9.0f;
  const float a00 = (6.f + mc.x) * inv6;
  const float a10 = mc.y * inv6;
  const float a01 = mr.x * inv6;
  const float a11 = (6.f + mr.y) * inv6;

  const pf2 c = g[1][P + 1];
  const pf2 U = mkf2(a00 - 1.f, a10);
  const pf2 V = mkf2(a01, a11 - 1.f);
  const pf2 Pv = c + U;
  const pf2 Mv = c - U;

  float errsum = 0.f;
  errsum += rdot(Mv - V, g[0][P]);      // k0 (-1,-1)
  errsum += rdot(c - V,  g[0][P + 1]);  // k1 ( 0,-1)
  errsum += rdot(Pv - V, g[0][P + 2]);  // k2 ( 1,-1)
  errsum += rdot(Mv,     g[1][P]);      // k3 (-1, 0)
  errsum += rdot(Pv,     g[1][P + 2]);  // k5 ( 1, 0)
  errsum += rdot(Mv + V, g[2][P]);      // k6 (-1, 1)
  errsum += rdot(c + V,  g[2][P + 1]);  // k7 ( 0, 1)
  errsum += rdot(Pv + V, g[2][P + 2]);  // k8 ( 1, 1)
  const float error = errsum * inv9;

  const float ex = fsqrt(fmaxf(fabsf(a00 * a11 - a10 * a01), 1e-10f));
  mo = ((ex > 0.5f) && (ex < 2.0f) && (error < 0.1f)) ? 1.0f : 0.0f;
  eo = (error > 0.1f) ? 1.0f : fminf(fmaxf(ex, 0.5f), 2.0f);
}

// ---- general path (zero-pad-minus-center), FULLY UNROLLED single pass ----
// Round-1 code (absmax 0.0). All 18 loads issue up-front; latency hidden.
__device__ __forceinline__ void general_pixel(const float* __restrict__ fx,
                                              const float* __restrict__ fy,
                                              int x, int y,
                                              float& mask_o, float& exp_o) {
  const int o = y * WW + x;
  const float fxc = fx[o], fyc = fy[o];

  float pp00 = 0.f, pp01 = 0.f, pp11 = 0.f;
  float m00 = 0.f, m01 = 0.f, m10 = 0.f, m11 = 0.f;
  float prxs[9], prys[9], ptxs[9], ptys[9];

#pragma unroll
  for (int di = -1; di <= 1; ++di) {
#pragma unroll
    for (int dj = -1; dj <= 1; ++dj) {
      const int k = (di + 1) * 3 + (dj + 1);
      const int yy = y + di;
      const int xx = x + dj;
      const bool in = (yy >= 0) && (yy < HH) && (xx >= 0) && (xx < WW);
      float prx, pry, ptx, pty;
      if (in) {
        prx = (float)dj;
        pry = (float)di;
        ptx = (float)dj + (fx[yy * WW + xx] - fxc);
        pty = (float)di + (fy[yy * WW + xx] - fyc);
      } else {
        prx = -(float)x;
        pry = -(float)y;
        ptx = -((float)x + fxc);
        pty = -((float)y + fyc);
      }
      prxs[k] = prx; prys[k] = pry; ptxs[k] = ptx; ptys[k] = pty;
      pp00 += prx * prx;
      pp01 += prx * pry;
      pp11 += pry * pry;
      m00 += ptx * prx;
      m01 += ptx * pry;
      m10 += pty * prx;
      m11 += pty * pry;
    }
  }

  const float det = fmaxf(pp00 * pp11 - pp01 * pp01, 1e-10f);
  const float i00 = pp11 / det;
  const float i01 = -pp01 / det;
  const float i11 = pp00 / det;

  const float a00 = m00 * i00 + m01 * i01;
  const float a01 = m00 * i01 + m01 * i11;
  const float a10 = m10 * i00 + m11 * i01;
  const float a11 = m10 * i01 + m11 * i11;

  float errsum = 0.f;
#pragma unroll
  for (int k = 0; k < 9; ++k) {
    const float rx = a00 * prxs[k] + a01 * prys[k] - ptxs[k];
    const float ry = a10 * prxs[k] + a11 * prys[k] - ptys[k];
    errsum += fsqrt(rx * rx + ry * ry);
  }
  const float error = errsum / 9.0f;

  const float ex = fsqrt(fmaxf(fabsf(a00 * a11 - a10 * a01), 1e-10f));
  mask_o = ((ex > 0.5f) && (ex < 2.0f) && (error < 0.1f)) ? 1.0f : 0.0f;
  exp_o = (error > 0.1f) ? 1.0f : fminf(fmaxf(ex, 0.5f), 2.0f);
}

__global__ __launch_bounds__(256) void monodisp_split(
    const float* __restrict__ flow,
    float* __restrict__ out_mask,
    float* __restrict__ out_exp) {
  if (blockIdx.x < N_INT_BLOCKS) {
    // ---------- interior: 2 px/thread, uniform waves ----------
    const int tid = blockIdx.x * 256 + threadIdx.x;
    if (tid >= N_INT_THREADS) return;
    const int pos = tid % POS_PER_ROW;
    const int t = tid / POS_PER_ROW;          // [0, 1016)
    const int y = t % INT_ROWS + 1;           // 1..254
    const int b = t / INT_ROWS;
    const int x0 = 1 + 2 * pos;               // odd; pixels x0, x0+1 in 1..830

    const float* __restrict__ fx = flow + (b * 2 + 0) * HWsz;
    const float* __restrict__ fy = flow + (b * 2 + 1) * HWsz;
    const int base = (y - 1) * WW + (x0 - 1); // even -> 8B aligned

    pf2 g[3][4];
#pragma unroll
    for (int r = 0; r < 3; ++r) {
      const float2 ax = *reinterpret_cast<const float2*>(fx + base + r * WW);
      const float2 bx = *reinterpret_cast<const float2*>(fx + base + r * WW + 2);
      const float2 ay = *reinterpret_cast<const float2*>(fy + base + r * WW);
      const float2 by = *reinterpret_cast<const float2*>(fy + base + r * WW + 2);
      g[r][0] = mkf2(ax.x, ay.x);
      g[r][1] = mkf2(ax.y, ay.y);
      g[r][2] = mkf2(bx.x, by.x);
      g[r][3] = mkf2(bx.y, by.y);
    }

    float m0, e0, m1, e1;
    interior_px<0>(g, m0, e0);
    interior_px<1>(g, m1, e1);

    const int oo = b * HWsz + y * WW + x0;
    out_mask[oo] = m0;
    out_mask[oo + 1] = m1;
    out_exp[oo] = e0;
    out_exp[oo + 1] = e1;
  } else {
    // ---------- border: dedicated blocks, unrolled general path ----------
    const int btid = (blockIdx.x - N_INT_BLOCKS) * 256 + threadIdx.x;
    if (btid >= N_BORDER) return;
    const int b = btid / BORDER_PER_B;
    const int r = btid % BORDER_PER_B;
    int x, y;
    if (r < WW) { y = 0; x = r; }
    else if (r < 2 * WW) { y = HH - 1; x = r - WW; }
    else if (r < 2 * WW + (HH - 2)) { x = 0; y = r - 2 * WW + 1; }
    else { x = WW - 1; y = r - (2 * WW + (HH - 2)) + 1; }

    const float* __restrict__ fx = flow + (b * 2 + 0) * HWsz;
    const float* __restrict__ fy = flow + (b * 2 + 1) * HWsz;
    float mo, eo;
    general_pixel(fx, fy, x, y, mo, eo);
    const int oo = b * HWsz + y * WW + x;
    out_mask[oo] = mo;
    out_exp[oo] = eo;
  }
}

extern "C" void kernel_launch(void* const* d_in, const int* in_sizes, int n_in,
                              void* d_out, int out_size, void* d_ws, size_t ws_size,
                              hipStream_t stream) {
  (void)in_sizes; (void)n_in; (void)d_ws; (void)ws_size; (void)out_size;
  const float* flow = (const float*)d_in[0];
  float* out = (float*)d_out;
  float* out_mask = out;
  float* out_exp = out + (size_t)BB * HH * WW;

  const int grid = N_INT_BLOCKS + N_BORDER_BLOCKS;  // 1682
  monodisp_split<<<grid, 256, 0, stream>>>(flow, out_mask, out_exp);
}